// Round 3
// baseline (804.700 us; speedup 1.0000x reference)
//
#include <hip/hip_runtime.h>

// Instant-NGP 2D hashgrid (L=16, T=2^20, F=2, N_MIN=16, b=2) + MLP 32->128->128->3.
//
// Three-pass structure:
//   Pass 0 (ngp_pack): hashed levels 6..15 f32[T][2] -> packed bf16 u32[T] (40 MiB).
//     One hashed level = 4 MiB = per-XCD L2 size.
//   Pass 1 (ngp_encode): level-major grid (16 levels x bpl blocks), 2 pts/thread.
//     Resident block window (~1700 blocks) < 1 level -> hot table fits one L2.
//     All 8 gather indices computed, 8 loads issued, sched_barrier(0), then math
//     (forces MLP; compiler previously serialized at VGPR=28).
//     Hashed gathers use nontemporal (L1 hit ~1%, skip line fills);
//     dense levels 0..5 read original f32 tables (small, L2-resident).
//   Pass 2 (ngp_mlp): round-1-verified fused MLP (both barriers, uniform loop)
//     + register prefetch of next tile's features (single delta vs round 1).
//
// mfma_f32_16x16x32_bf16 layouts (HW-verified per guide):
//   A[m][k]: m = lane&15, k = (lane>>4)*8 + j   (8 bf16 / lane)
//   B[k][n]: n = lane&15, k = (lane>>4)*8 + j
//   D[m][n]: n = lane&15, m = (lane>>4)*4 + r   (4 f32 / lane)

#define T_SIZE  (1u << 20)
#define HASH_Y  2654435761u
#define NLVL    16
#define MAXPTS  (1u << 20)

typedef __bf16 bf16x8 __attribute__((ext_vector_type(8)));
typedef float f32x4 __attribute__((ext_vector_type(4)));
typedef unsigned short u16x8 __attribute__((ext_vector_type(8)));
typedef unsigned short u16x4 __attribute__((ext_vector_type(4)));

// 64 MiB packed-bf16 table (only levels 6..15 used) + 64 MiB feature scratch.
__device__ unsigned int g_tbl[NLVL * T_SIZE];
__device__ unsigned int g_feat[NLVL * MAXPTS];

static __device__ __forceinline__ unsigned short f2bf(float f) {
    union { float f; unsigned u; } v; v.f = f;
    unsigned u = v.u;
    u += 0x7fffu + ((u >> 16) & 1u);   // round-to-nearest-even
    return (unsigned short)(u >> 16);
}

static __device__ __forceinline__ unsigned packbf(float a, float b) {
    return (unsigned)f2bf(a) | ((unsigned)f2bf(b) << 16);
}

static __device__ __forceinline__ float bflo(unsigned p) {
    union { unsigned u; float f; } v; v.u = p << 16; return v.f;
}
static __device__ __forceinline__ float bfhi(unsigned p) {
    union { unsigned u; float f; } v; v.u = p & 0xffff0000u; return v.f;
}

static __device__ __forceinline__ f32x4 mfma16(u16x8 a, u16x8 b, f32x4 c) {
    return __builtin_amdgcn_mfma_f32_16x16x32_bf16(
        __builtin_bit_cast(bf16x8, a), __builtin_bit_cast(bf16x8, b), c, 0, 0, 0);
}

// ---------------- Pass 0: pack hashed-level tables to bf16 pairs ----------------
// Levels 6..15 only: 10M entries; each thread packs 4 (2x float4 in, 1x uint4 out).
__global__ __launch_bounds__(256)
void ngp_pack(const float* __restrict__ tables)
{
    unsigned i = 6u * T_SIZE + (blockIdx.x * 256u + threadIdx.x) * 4u;   // entry index
    const float4* s = (const float4*)(tables + (size_t)i * 2);
    float4 a = s[0], b = s[1];
    uint4 o;
    o.x = packbf(a.x, a.y);
    o.y = packbf(a.z, a.w);
    o.z = packbf(b.x, b.y);
    o.w = packbf(b.z, b.w);
    *(uint4*)(g_tbl + i) = o;
}

// ---------------- Pass 1: level-major hashgrid encode ----------------
// blockIdx = lvl * bpl + blk; each block encodes 512 consecutive points at
// one level; each thread does 2 consecutive points (uint2 feature store).
__global__ __launch_bounds__(256)
void ngp_encode(const float* __restrict__ uv, const float* __restrict__ tables,
                int npts, int bpl)
{
    const int bid = blockIdx.x;
    const int lvl = bid / bpl;               // scalar div, once per block
    const int blk = bid - lvl * bpl;
    const int base = (blk << 9) + (threadIdx.x << 1);
    if (base >= npts) return;

    const unsigned res = 16u << lvl;
    const float fres = (float)res;
    const unsigned rp1 = res + 1u;
    const unsigned mask = T_SIZE - 1u;
    const bool dense = lvl < 6;              // (res+1)^2 <= T  <=>  lvl <= 5

    // uv for 2 consecutive points: one float4 load.
    const float4 u4 = *(const float4*)(uv + (size_t)base * 2);
    float pxa[2] = {u4.x, u4.z};
    float pya[2] = {u4.y, u4.w};

    // Phase 1: all 8 indices.
    unsigned idx[2][4];
    float wx[2], wy[2];
#pragma unroll
    for (int u = 0; u < 2; ++u) {
        float px = pxa[u] * fres, py = pya[u] * fres;
        float fx = floorf(px), fy = floorf(py);
        wx[u] = px - fx; wy[u] = py - fy;
        unsigned cx = (unsigned)fx, cy = (unsigned)fy;
        if (dense) {
            idx[u][0] = cx + cy * rp1;
            idx[u][1] = cx + (cy + 1u) * rp1;
            idx[u][2] = idx[u][0] + 1u;
            idx[u][3] = idx[u][1] + 1u;
        } else {
            unsigned hy0 = cy * HASH_Y, hy1 = (cy + 1u) * HASH_Y;
            idx[u][0] = (cx ^ hy0) & mask;
            idx[u][1] = (cx ^ hy1) & mask;
            idx[u][2] = ((cx + 1u) ^ hy0) & mask;
            idx[u][3] = ((cx + 1u) ^ hy1) & mask;
        }
    }

    unsigned pk[2];
    if (dense) {
        // Dense: original f32 tables (small, L2-resident; full precision).
        const float2* __restrict__ t2 = (const float2*)tables + (size_t)lvl * T_SIZE;
        float2 e[2][4];
#pragma unroll
        for (int u = 0; u < 2; ++u)
#pragma unroll
            for (int c = 0; c < 4; ++c) e[u][c] = t2[idx[u][c]];
        __builtin_amdgcn_sched_barrier(0);   // all 8 loads issued before math
#pragma unroll
        for (int u = 0; u < 2; ++u) {
            float w00 = (1.f - wx[u]) * (1.f - wy[u]);
            float w01 = (1.f - wx[u]) * wy[u];
            float w10 = wx[u] * (1.f - wy[u]);
            float w11 = wx[u] * wy[u];
            float g0 = w00 * e[u][0].x + w01 * e[u][1].x + w10 * e[u][2].x + w11 * e[u][3].x;
            float g1 = w00 * e[u][0].y + w01 * e[u][1].y + w10 * e[u][2].y + w11 * e[u][3].y;
            pk[u] = packbf(g0, g1);
        }
    } else {
        // Hashed: packed bf16 table, nontemporal (L1 hit ~1% -> skip line fills).
        const unsigned* __restrict__ tl = g_tbl + (size_t)lvl * T_SIZE;
        unsigned e[2][4];
#pragma unroll
        for (int u = 0; u < 2; ++u)
#pragma unroll
            for (int c = 0; c < 4; ++c)
                e[u][c] = __builtin_nontemporal_load(tl + idx[u][c]);
        __builtin_amdgcn_sched_barrier(0);   // all 8 loads issued before math
#pragma unroll
        for (int u = 0; u < 2; ++u) {
            float w00 = (1.f - wx[u]) * (1.f - wy[u]);
            float w01 = (1.f - wx[u]) * wy[u];
            float w10 = wx[u] * (1.f - wy[u]);
            float w11 = wx[u] * wy[u];
            float g0 = w00 * bflo(e[u][0]) + w01 * bflo(e[u][1]) + w10 * bflo(e[u][2]) + w11 * bflo(e[u][3]);
            float g1 = w00 * bfhi(e[u][0]) + w01 * bfhi(e[u][1]) + w10 * bfhi(e[u][2]) + w11 * bfhi(e[u][3]);
            pk[u] = packbf(g0, g1);
        }
    }
    *(uint2*)(g_feat + (size_t)lvl * npts + base) = make_uint2(pk[0], pk[1]);
}

// ---------------- Pass 2: fused MLP 32->128->128->3 ----------------
// LDS: w2T[out 128][in 136 pad] bf16 (34816 B) + h[4 waves][16 pts][136 pad]
// (17408 B) + biases (1024 B) = 53248 B; ~3 blocks/CU by LDS.
// Round-1-verified structure (both barriers, uniform niter loop); single
// delta: next tile's features prefetched into registers during compute.
__global__ __launch_bounds__(256, 2)
void ngp_mlp(const float* __restrict__ w1, const float* __restrict__ b1,
             const float* __restrict__ w2, const float* __restrict__ b2,
             const float* __restrict__ w3, const float* __restrict__ b3,
             float* __restrict__ out, int npts)
{
    __shared__ __align__(16) unsigned short w2T[128 * 136];
    __shared__ __align__(16) unsigned short hbuf[4 * 16 * 136];
    __shared__ float b1s[128], b2s[128];

    const int tid = threadIdx.x;
    for (int e = tid; e < 128 * 128; e += 256) {        // w2 is [in][out]; store w2T[out][in]
        int i = e >> 7, o = e & 127;
        w2T[o * 136 + i] = f2bf(w2[e]);
    }
    if (tid < 128) { b1s[tid] = b1[tid]; b2s[tid] = b2[tid]; }
    __syncthreads();

    const int lane = tid & 63;
    const int wv = tid >> 6;
    const int lanelo = lane & 15;
    const int quad = lane >> 4;

    // Register-resident A-fragments: layer 1 (w1^T [128x32]) and layer 3 (w3^T [3x128], rows 3..15 zero).
    u16x8 a1[8];
#pragma unroll
    for (int mt = 0; mt < 8; ++mt)
#pragma unroll
        for (int j = 0; j < 8; ++j)
            a1[mt][j] = f2bf(w1[(quad * 8 + j) * 128 + mt * 16 + lanelo]);  // w1[k][m]

    u16x8 a3[4];
#pragma unroll
    for (int ks = 0; ks < 4; ++ks)
#pragma unroll
        for (int j = 0; j < 8; ++j) {
            int k = ks * 32 + quad * 8 + j;
            a3[ks][j] = (lanelo < 3) ? f2bf(w3[k * 3 + lanelo]) : (unsigned short)0;  // w3[k][m]
        }
    float b3r0 = b3[0], b3r1 = b3[1], b3r2 = b3[2];

    const int NT = npts >> 4;                 // 16-point tiles
    const int nwaves = gridDim.x * 4;
    const int gwave = blockIdx.x * 4 + wv;
    const int niter = (NT + nwaves - 1) / nwaves;   // uniform trip count (syncthreads-safe)

    unsigned short* hp = hbuf + (wv * 16 + lanelo) * 136;   // this lane's point-row
    const int lvlbase = quad << 2;            // this lane's 4 levels

    // Preload iter-0 features.
    unsigned c0 = 0, c1 = 0, c2 = 0, c3 = 0;
    if (gwave < NT) {
        int pt0 = (gwave << 4) + lanelo;
        c0 = g_feat[(size_t)(lvlbase + 0) * npts + pt0];
        c1 = g_feat[(size_t)(lvlbase + 1) * npts + pt0];
        c2 = g_feat[(size_t)(lvlbase + 2) * npts + pt0];
        c3 = g_feat[(size_t)(lvlbase + 3) * npts + pt0];
    }

    for (int it = 0; it < niter; ++it) {
        int tile = gwave + it * nwaves;
        bool act = tile < NT;
        int pt = (tile << 4) + lanelo;

        if (act) {
            // ---- B-fragment from (pre)loaded feats ----
            u16x8 xb;
            xb[0] = (unsigned short)(c0 & 0xffffu); xb[1] = (unsigned short)(c0 >> 16);
            xb[2] = (unsigned short)(c1 & 0xffffu); xb[3] = (unsigned short)(c1 >> 16);
            xb[4] = (unsigned short)(c2 & 0xffffu); xb[5] = (unsigned short)(c2 >> 16);
            xb[6] = (unsigned short)(c3 & 0xffffu); xb[7] = (unsigned short)(c3 >> 16);

            // ---- prefetch next tile's feats (latency hidden under MFMA/LDS/barriers) ----
            int tn = tile + nwaves;
            if (tn < NT) {
                int ptn = (tn << 4) + lanelo;
                c0 = g_feat[(size_t)(lvlbase + 0) * npts + ptn];
                c1 = g_feat[(size_t)(lvlbase + 1) * npts + ptn];
                c2 = g_feat[(size_t)(lvlbase + 2) * npts + ptn];
                c3 = g_feat[(size_t)(lvlbase + 3) * npts + ptn];
            }

            // ---- layer 1: 8 MFMAs, K=32 in one shot ----
            f32x4 z = {0.f, 0.f, 0.f, 0.f};
            f32x4 d[8];
#pragma unroll
            for (int mt = 0; mt < 8; ++mt) d[mt] = mfma16(a1[mt], xb, z);
#pragma unroll
            for (int mt = 0; mt < 8; ++mt) {
                u16x4 pk;
#pragma unroll
                for (int r = 0; r < 4; ++r) {
                    float hv = d[mt][r] + b1s[mt * 16 + quad * 4 + r];
                    pk[r] = f2bf(fmaxf(hv, 0.f));
                }
                *(u16x4*)(hp + mt * 16 + quad * 4) = pk;
            }
        }
        __syncthreads();
        if (act) {
            // ---- layer 2: K=128 in 4 steps x 8 m-tiles ----
            f32x4 z = {0.f, 0.f, 0.f, 0.f};
            f32x4 e[8];
#pragma unroll
            for (int mt = 0; mt < 8; ++mt) e[mt] = z;
#pragma unroll
            for (int ks = 0; ks < 4; ++ks) {
                u16x8 bb = *(const u16x8*)(hp + ks * 32 + quad * 8);   // h1[pt][k..k+7]
#pragma unroll
                for (int mt = 0; mt < 8; ++mt) {
                    u16x8 aa = *(const u16x8*)(w2T + (mt * 16 + lanelo) * 136 + ks * 32 + quad * 8);
                    e[mt] = mfma16(aa, bb, e[mt]);
                }
            }
            // bias + relu + pack back to same LDS rows (all reads above precede these writes; DS in-order per wave)
#pragma unroll
            for (int mt = 0; mt < 8; ++mt) {
                u16x4 pk;
#pragma unroll
                for (int r = 0; r < 4; ++r) {
                    float hv = e[mt][r] + b2s[mt * 16 + quad * 4 + r];
                    pk[r] = f2bf(fmaxf(hv, 0.f));
                }
                *(u16x4*)(hp + mt * 16 + quad * 4) = pk;
            }
        }
        __syncthreads();
        if (act) {
            // ---- layer 3: 4 MFMAs, rows 0..2 = RGB logits ----
            f32x4 o3 = {0.f, 0.f, 0.f, 0.f};
#pragma unroll
            for (int ks = 0; ks < 4; ++ks) {
                u16x8 bb = *(const u16x8*)(hp + ks * 32 + quad * 8);
                o3 = mfma16(a3[ks], bb, o3);
            }
            if (quad == 0) {   // D rows quad*4+r -> rows 0..2 live in quad 0
                float* op = out + (size_t)pt * 3;
                op[0] = 1.f / (1.f + expf(-(o3[0] + b3r0)));
                op[1] = 1.f / (1.f + expf(-(o3[1] + b3r1)));
                op[2] = 1.f / (1.f + expf(-(o3[2] + b3r2)));
            }
        }
    }
}

extern "C" void kernel_launch(void* const* d_in, const int* in_sizes, int n_in,
                              void* d_out, int out_size, void* d_ws, size_t ws_size,
                              hipStream_t stream) {
    const float* uv     = (const float*)d_in[0];
    const float* tables = (const float*)d_in[1];
    const float* w1     = (const float*)d_in[2];
    const float* b1     = (const float*)d_in[3];
    const float* w2     = (const float*)d_in[4];
    const float* b2     = (const float*)d_in[5];
    const float* w3     = (const float*)d_in[6];
    const float* b3     = (const float*)d_in[7];
    float* out = (float*)d_out;
    int npts = in_sizes[0] / 2;          // uv is [N,2]

    // Pass 0: bf16-pack hashed levels 6..15 (10M entries, 4/thread).
    hipLaunchKernelGGL(ngp_pack, dim3((10u * T_SIZE) / 1024), dim3(256), 0, stream,
                       tables);

    // Pass 1: level-major encode. bpl blocks of 512 points per level.
    int bpl = (npts + 511) >> 9;
    hipLaunchKernelGGL(ngp_encode, dim3(NLVL * bpl), dim3(256), 0, stream,
                       uv, tables, npts, bpl);

    // Pass 2: fused MLP. 2048 blocks x 4 waves = 8192 wave-slots.
    hipLaunchKernelGGL(ngp_mlp, dim3(2048), dim3(256), 0, stream,
                       w1, b1, w2, b2, w3, b3, out, npts);
}

// Round 4
// 522.156 us; speedup vs baseline: 1.5411x; 1.5411x over previous
//
#include <hip/hip_runtime.h>

// Instant-NGP 2D hashgrid (L=16, T=2^20, F=2, N_MIN=16, b=2) + MLP 32->128->128->3.
//
// Three-pass structure:
//   Pass 0 (ngp_pack): tables f32[L][T][2] -> packed bf16 pairs u32[L][T] (64 MiB).
//     One hashed level = 4 MiB = per-XCD L2 size.
//   Pass 1 (ngp_encode): level-major grid (16 levels x bpl blocks), 4 pts/thread.
//     Resident block window covers ~1 level at a time -> hot table fits L2.
//     All 16 gather indices computed, ALL 16 loads issued as one batch,
//     sched_barrier(0), then interpolation math (forces 16-deep MLP per
//     thread; rounds 2/3 only achieved 4-8 in flight, VGPR 24-28).
//     NO nontemporal: round 3 proved nt defeats L2 retention on gfx950
//     (FETCH 320MB -> 1.12GB, dur 255 -> 523us).
//   Pass 2 (ngp_mlp): round-1-verified fused MLP (both barriers, uniform loop)
//     + register prefetch of next tile's features.
//
// mfma_f32_16x16x32_bf16 layouts (HW-verified per guide):
//   A[m][k]: m = lane&15, k = (lane>>4)*8 + j   (8 bf16 / lane)
//   B[k][n]: n = lane&15, k = (lane>>4)*8 + j
//   D[m][n]: n = lane&15, m = (lane>>4)*4 + r   (4 f32 / lane)

#define T_SIZE  (1u << 20)
#define HASH_Y  2654435761u
#define NLVL    16
#define MAXPTS  (1u << 20)

typedef __bf16 bf16x8 __attribute__((ext_vector_type(8)));
typedef float f32x4 __attribute__((ext_vector_type(4)));
typedef unsigned short u16x8 __attribute__((ext_vector_type(8)));
typedef unsigned short u16x4 __attribute__((ext_vector_type(4)));

// 64 MiB packed-bf16 table + 64 MiB feature scratch.
__device__ unsigned int g_tbl[NLVL * T_SIZE];
__device__ unsigned int g_feat[NLVL * MAXPTS];

static __device__ __forceinline__ unsigned short f2bf(float f) {
    union { float f; unsigned u; } v; v.f = f;
    unsigned u = v.u;
    u += 0x7fffu + ((u >> 16) & 1u);   // round-to-nearest-even
    return (unsigned short)(u >> 16);
}

static __device__ __forceinline__ unsigned packbf(float a, float b) {
    return (unsigned)f2bf(a) | ((unsigned)f2bf(b) << 16);
}

static __device__ __forceinline__ float bflo(unsigned p) {
    union { unsigned u; float f; } v; v.u = p << 16; return v.f;
}
static __device__ __forceinline__ float bfhi(unsigned p) {
    union { unsigned u; float f; } v; v.u = p & 0xffff0000u; return v.f;
}

static __device__ __forceinline__ f32x4 mfma16(u16x8 a, u16x8 b, f32x4 c) {
    return __builtin_amdgcn_mfma_f32_16x16x32_bf16(
        __builtin_bit_cast(bf16x8, a), __builtin_bit_cast(bf16x8, b), c, 0, 0, 0);
}

// ---------------- Pass 0: pack tables to bf16 pairs ----------------
// 16M entries; each thread packs 4 (2x float4 in, 1x uint4 out).
__global__ __launch_bounds__(256)
void ngp_pack(const float* __restrict__ tables)
{
    unsigned i = (blockIdx.x * 256u + threadIdx.x) * 4u;   // entry index
    const float4* s = (const float4*)(tables + (size_t)i * 2);
    float4 a = s[0], b = s[1];
    uint4 o;
    o.x = packbf(a.x, a.y);
    o.y = packbf(a.z, a.w);
    o.z = packbf(b.x, b.y);
    o.w = packbf(b.z, b.w);
    *(uint4*)(g_tbl + i) = o;
}

// ---------------- Pass 1: level-major hashgrid encode ----------------
// blockIdx = lvl * bpl + blk; each block encodes 1024 consecutive points at
// one level; each thread does 4 consecutive points (uint4 feature store).
__global__ __launch_bounds__(256)
void ngp_encode(const float* __restrict__ uv, int npts, int bpl)
{
    const int bid = blockIdx.x;
    const int lvl = bid / bpl;               // scalar div, once per block
    const int blk = bid - lvl * bpl;
    const int base = (blk << 10) + (threadIdx.x << 2);
    if (base >= npts) return;

    const unsigned res = 16u << lvl;
    const float fres = (float)res;
    const unsigned rp1 = res + 1u;
    const unsigned mask = T_SIZE - 1u;
    const bool dense = lvl < 6;              // (res+1)^2 <= T  <=>  lvl <= 5
    const unsigned* __restrict__ tl = g_tbl + (size_t)lvl * T_SIZE;

    // uv for 4 consecutive points: 32 B, two float4 loads.
    const float4* u4 = (const float4*)(uv + (size_t)base * 2);
    float4 ua = u4[0], ub = u4[1];
    float pxa[4] = {ua.x, ua.z, ub.x, ub.z};
    float pya[4] = {ua.y, ua.w, ub.y, ub.w};

    // Phase 1: all 16 indices.
    unsigned i00[4], i01[4], i10[4], i11[4];
    float wx[4], wy[4];
#pragma unroll
    for (int u = 0; u < 4; ++u) {
        float px = pxa[u] * fres, py = pya[u] * fres;
        float fx = floorf(px), fy = floorf(py);
        wx[u] = px - fx; wy[u] = py - fy;
        unsigned cx = (unsigned)fx, cy = (unsigned)fy;
        unsigned hy0 = cy * HASH_Y, hy1 = (cy + 1u) * HASH_Y;
        i00[u] = dense ? (cx + cy * rp1)              : ((cx ^ hy0) & mask);
        i01[u] = dense ? (cx + (cy + 1u) * rp1)       : ((cx ^ hy1) & mask);
        i10[u] = dense ? (cx + 1u + cy * rp1)         : (((cx + 1u) ^ hy0) & mask);
        i11[u] = dense ? (cx + 1u + (cy + 1u) * rp1)  : (((cx + 1u) ^ hy1) & mask);
    }
    // Phase 2: all 16 gathers issued as ONE batch; sched_barrier keeps the
    // interpolation math from being interleaved into the load stream, so all
    // 16 stay in flight (16-deep MLP per thread).
    unsigned e00[4], e01[4], e10[4], e11[4];
#pragma unroll
    for (int u = 0; u < 4; ++u) {
        e00[u] = tl[i00[u]];
        e01[u] = tl[i01[u]];
        e10[u] = tl[i10[u]];
        e11[u] = tl[i11[u]];
    }
    __builtin_amdgcn_sched_barrier(0);
    // Phase 3: bilinear interp + pack.
    unsigned pk[4];
#pragma unroll
    for (int u = 0; u < 4; ++u) {
        float w00 = (1.f - wx[u]) * (1.f - wy[u]);
        float w01 = (1.f - wx[u]) * wy[u];
        float w10 = wx[u] * (1.f - wy[u]);
        float w11 = wx[u] * wy[u];
        float g0 = w00 * bflo(e00[u]) + w01 * bflo(e01[u]) + w10 * bflo(e10[u]) + w11 * bflo(e11[u]);
        float g1 = w00 * bfhi(e00[u]) + w01 * bfhi(e01[u]) + w10 * bfhi(e10[u]) + w11 * bfhi(e11[u]);
        pk[u] = packbf(g0, g1);
    }
    *(uint4*)(g_feat + (size_t)lvl * npts + base) = make_uint4(pk[0], pk[1], pk[2], pk[3]);
}

// ---------------- Pass 2: fused MLP 32->128->128->3 ----------------
// LDS: w2T[out 128][in 136 pad] bf16 (34816 B) + h[4 waves][16 pts][136 pad]
// (17408 B) + biases (1024 B) = 53248 B; ~3 blocks/CU by LDS.
// Round-1-verified structure (both barriers, uniform niter loop); single
// delta: next tile's features prefetched into registers during compute.
__global__ __launch_bounds__(256, 2)
void ngp_mlp(const float* __restrict__ w1, const float* __restrict__ b1,
             const float* __restrict__ w2, const float* __restrict__ b2,
             const float* __restrict__ w3, const float* __restrict__ b3,
             float* __restrict__ out, int npts)
{
    __shared__ __align__(16) unsigned short w2T[128 * 136];
    __shared__ __align__(16) unsigned short hbuf[4 * 16 * 136];
    __shared__ float b1s[128], b2s[128];

    const int tid = threadIdx.x;
    for (int e = tid; e < 128 * 128; e += 256) {        // w2 is [in][out]; store w2T[out][in]
        int i = e >> 7, o = e & 127;
        w2T[o * 136 + i] = f2bf(w2[e]);
    }
    if (tid < 128) { b1s[tid] = b1[tid]; b2s[tid] = b2[tid]; }
    __syncthreads();

    const int lane = tid & 63;
    const int wv = tid >> 6;
    const int lanelo = lane & 15;
    const int quad = lane >> 4;

    // Register-resident A-fragments: layer 1 (w1^T [128x32]) and layer 3 (w3^T [3x128], rows 3..15 zero).
    u16x8 a1[8];
#pragma unroll
    for (int mt = 0; mt < 8; ++mt)
#pragma unroll
        for (int j = 0; j < 8; ++j)
            a1[mt][j] = f2bf(w1[(quad * 8 + j) * 128 + mt * 16 + lanelo]);  // w1[k][m]

    u16x8 a3[4];
#pragma unroll
    for (int ks = 0; ks < 4; ++ks)
#pragma unroll
        for (int j = 0; j < 8; ++j) {
            int k = ks * 32 + quad * 8 + j;
            a3[ks][j] = (lanelo < 3) ? f2bf(w3[k * 3 + lanelo]) : (unsigned short)0;  // w3[k][m]
        }
    float b3r0 = b3[0], b3r1 = b3[1], b3r2 = b3[2];

    const int NT = npts >> 4;                 // 16-point tiles
    const int nwaves = gridDim.x * 4;
    const int gwave = blockIdx.x * 4 + wv;
    const int niter = (NT + nwaves - 1) / nwaves;   // uniform trip count (syncthreads-safe)

    unsigned short* hp = hbuf + (wv * 16 + lanelo) * 136;   // this lane's point-row
    const int lvlbase = quad << 2;            // this lane's 4 levels

    // Preload iter-0 features.
    unsigned c0 = 0, c1 = 0, c2 = 0, c3 = 0;
    if (gwave < NT) {
        int pt0 = (gwave << 4) + lanelo;
        c0 = g_feat[(size_t)(lvlbase + 0) * npts + pt0];
        c1 = g_feat[(size_t)(lvlbase + 1) * npts + pt0];
        c2 = g_feat[(size_t)(lvlbase + 2) * npts + pt0];
        c3 = g_feat[(size_t)(lvlbase + 3) * npts + pt0];
    }

    for (int it = 0; it < niter; ++it) {
        int tile = gwave + it * nwaves;
        bool act = tile < NT;
        int pt = (tile << 4) + lanelo;

        if (act) {
            // ---- B-fragment from (pre)loaded feats ----
            u16x8 xb;
            xb[0] = (unsigned short)(c0 & 0xffffu); xb[1] = (unsigned short)(c0 >> 16);
            xb[2] = (unsigned short)(c1 & 0xffffu); xb[3] = (unsigned short)(c1 >> 16);
            xb[4] = (unsigned short)(c2 & 0xffffu); xb[5] = (unsigned short)(c2 >> 16);
            xb[6] = (unsigned short)(c3 & 0xffffu); xb[7] = (unsigned short)(c3 >> 16);

            // ---- prefetch next tile's feats (latency hidden under MFMA/LDS/barriers) ----
            int tn = tile + nwaves;
            if (tn < NT) {
                int ptn = (tn << 4) + lanelo;
                c0 = g_feat[(size_t)(lvlbase + 0) * npts + ptn];
                c1 = g_feat[(size_t)(lvlbase + 1) * npts + ptn];
                c2 = g_feat[(size_t)(lvlbase + 2) * npts + ptn];
                c3 = g_feat[(size_t)(lvlbase + 3) * npts + ptn];
            }

            // ---- layer 1: 8 MFMAs, K=32 in one shot ----
            f32x4 z = {0.f, 0.f, 0.f, 0.f};
            f32x4 d[8];
#pragma unroll
            for (int mt = 0; mt < 8; ++mt) d[mt] = mfma16(a1[mt], xb, z);
#pragma unroll
            for (int mt = 0; mt < 8; ++mt) {
                u16x4 pk;
#pragma unroll
                for (int r = 0; r < 4; ++r) {
                    float hv = d[mt][r] + b1s[mt * 16 + quad * 4 + r];
                    pk[r] = f2bf(fmaxf(hv, 0.f));
                }
                *(u16x4*)(hp + mt * 16 + quad * 4) = pk;
            }
        }
        __syncthreads();
        if (act) {
            // ---- layer 2: K=128 in 4 steps x 8 m-tiles ----
            f32x4 z = {0.f, 0.f, 0.f, 0.f};
            f32x4 e[8];
#pragma unroll
            for (int mt = 0; mt < 8; ++mt) e[mt] = z;
#pragma unroll
            for (int ks = 0; ks < 4; ++ks) {
                u16x8 bb = *(const u16x8*)(hp + ks * 32 + quad * 8);   // h1[pt][k..k+7]
#pragma unroll
                for (int mt = 0; mt < 8; ++mt) {
                    u16x8 aa = *(const u16x8*)(w2T + (mt * 16 + lanelo) * 136 + ks * 32 + quad * 8);
                    e[mt] = mfma16(aa, bb, e[mt]);
                }
            }
            // bias + relu + pack back to same LDS rows (all reads above precede these writes; DS in-order per wave)
#pragma unroll
            for (int mt = 0; mt < 8; ++mt) {
                u16x4 pk;
#pragma unroll
                for (int r = 0; r < 4; ++r) {
                    float hv = e[mt][r] + b2s[mt * 16 + quad * 4 + r];
                    pk[r] = f2bf(fmaxf(hv, 0.f));
                }
                *(u16x4*)(hp + mt * 16 + quad * 4) = pk;
            }
        }
        __syncthreads();
        if (act) {
            // ---- layer 3: 4 MFMAs, rows 0..2 = RGB logits ----
            f32x4 o3 = {0.f, 0.f, 0.f, 0.f};
#pragma unroll
            for (int ks = 0; ks < 4; ++ks) {
                u16x8 bb = *(const u16x8*)(hp + ks * 32 + quad * 8);
                o3 = mfma16(a3[ks], bb, o3);
            }
            if (quad == 0) {   // D rows quad*4+r -> rows 0..2 live in quad 0
                float* op = out + (size_t)pt * 3;
                op[0] = 1.f / (1.f + expf(-(o3[0] + b3r0)));
                op[1] = 1.f / (1.f + expf(-(o3[1] + b3r1)));
                op[2] = 1.f / (1.f + expf(-(o3[2] + b3r2)));
            }
        }
    }
}

extern "C" void kernel_launch(void* const* d_in, const int* in_sizes, int n_in,
                              void* d_out, int out_size, void* d_ws, size_t ws_size,
                              hipStream_t stream) {
    const float* uv     = (const float*)d_in[0];
    const float* tables = (const float*)d_in[1];
    const float* w1     = (const float*)d_in[2];
    const float* b1     = (const float*)d_in[3];
    const float* w2     = (const float*)d_in[4];
    const float* b2     = (const float*)d_in[5];
    const float* w3     = (const float*)d_in[6];
    const float* b3     = (const float*)d_in[7];
    float* out = (float*)d_out;
    int npts = in_sizes[0] / 2;          // uv is [N,2]

    // Pass 0: bf16-pack all 16M table entries. 16384 blocks x 256 thr x 4 entries.
    hipLaunchKernelGGL(ngp_pack, dim3((NLVL * T_SIZE) / 1024), dim3(256), 0, stream,
                       tables);

    // Pass 1: level-major encode. bpl blocks of 1024 points per level.
    int bpl = (npts + 1023) >> 10;
    hipLaunchKernelGGL(ngp_encode, dim3(NLVL * bpl), dim3(256), 0, stream,
                       uv, npts, bpl);

    // Pass 2: fused MLP. 2048 blocks x 4 waves = 8192 wave-slots.
    hipLaunchKernelGGL(ngp_mlp, dim3(2048), dim3(256), 0, stream,
                       w1, b1, w2, b2, w3, b3, out, npts);
}